// Round 1
// baseline (1230.361 us; speedup 1.0000x reference)
//
#include <hip/hip_runtime.h>
#include <hip/hip_bf16.h>

// ---------------------------------------------------------------------------
// MEATransformer pipeline for MI355X (gfx950)
// Heavy op: sims = qn @ weight  (256x256 @ 256x500000, fp32 in HBM)
// Strategy: bf16 MFMA streaming GEMM fused with per-query top-8 tracking,
// then exact fp32 rescue of top-8 -> exact top-3 indices/scores.
// Small transformer done with bf16 MFMA GEMMs over pre-transposed weights.
// ---------------------------------------------------------------------------

#define N_DB    500000
#define D_DIM   256
#define B_Q     256
#define NLBL    12
#define NCHUNKS 7813      // ceil(500000/64)
#define K2_GRID 256

typedef __attribute__((ext_vector_type(8))) short short8;
typedef __attribute__((ext_vector_type(4))) float f32x4;
typedef unsigned short u16;
typedef unsigned int   u32;

static __device__ __forceinline__ u16 f2bf(float f) {
  __hip_bfloat16 h = __float2bfloat16(f);
  return __builtin_bit_cast(u16, h);
}
static __device__ __forceinline__ float bf2f(u16 u) {
  u32 x = ((u32)u) << 16;
  return __builtin_bit_cast(float, x);
}
static __device__ __forceinline__ void gload16(const void* g, void* l) {
  __builtin_amdgcn_global_load_lds((const __attribute__((address_space(1))) void*)g,
                                   (__attribute__((address_space(3))) void*)l,
                                   16, 0, 0);
}
#define MFMA16x16(a, b, c) __builtin_amdgcn_mfma_f32_16x16x32_bf16((a), (b), (c), 0, 0, 0)

// ---------------------------------------------------------------------------
// K1: normalize queries -> qn (f32) and qn_bf (bf16)
// ---------------------------------------------------------------------------
__global__ __launch_bounds__(256)
void prep_queries(const float* __restrict__ queries, float* __restrict__ qn,
                  u16* __restrict__ qn_bf)
{
  __shared__ float wsum[4];
  const int b = blockIdx.x, t = threadIdx.x;
  float v = queries[b*D_DIM + t];
  float s = v*v;
#pragma unroll
  for (int off = 32; off; off >>= 1) s += __shfl_xor(s, off);
  if ((t & 63) == 0) wsum[t >> 6] = s;
  __syncthreads();
  float tot = wsum[0] + wsum[1] + wsum[2] + wsum[3];
  float rn = 1.0f / sqrtf(tot);
  float o = v * rn;
  qn[b*D_DIM + t] = o;
  qn_bf[b*D_DIM + t] = f2bf(o);
}

// ---------------------------------------------------------------------------
// T1: transpose+convert small weights to bf16 [out_col][in_dim] layouts.
// grid = 2304 rows: [0,1536) WqkvT, [1536,2048) WoT, [2048,2304) denseT
// ---------------------------------------------------------------------------
__global__ __launch_bounds__(256)
void transp(const float* __restrict__ Wq, const float* __restrict__ Wk,
            const float* __restrict__ Wv, const float* __restrict__ Wo,
            const float* __restrict__ dw, const float* __restrict__ bq,
            const float* __restrict__ bk, const float* __restrict__ bv,
            u16* __restrict__ WqkvT, u16* __restrict__ WoT,
            u16* __restrict__ denseT, float* __restrict__ bqkv)
{
  const int r = blockIdx.x, d = threadIdx.x;
  if (r < 1536) {
    const int l = r / 768, j = r % 768;
    const float* M_; const float* b_; int jj;
    if (j < 256)      { M_ = Wq; b_ = bq; jj = j; }
    else if (j < 512) { M_ = Wk; b_ = bk; jj = j - 256; }
    else              { M_ = Wv; b_ = bv; jj = j - 512; }
    WqkvT[(size_t)r*256 + d] = f2bf(M_[((size_t)l*256 + d)*256 + jj]);
    if (d == 0) bqkv[r] = b_[l*256 + jj];
  } else if (r < 2048) {
    const int i = r - 1536; const int l = i >> 8, n2 = i & 255;
    WoT[(size_t)i*256 + d] = f2bf(Wo[((size_t)l*256 + d)*256 + n2]);
  } else {
    const int n2 = r - 2048;
    denseT[(size_t)n2*256 + d] = f2bf(dw[(size_t)d*256 + n2]);
  }
}

// ---------------------------------------------------------------------------
// K2: streaming sims GEMM + per-(block,query) top-8.
// block = 512 thr (8 waves). Wave w owns query rows [32w, 32w+32).
// Chunk = 64 db columns; K staged in 64-row fp32 slabs, double-buffered via
// global_load_lds (2-phase pipeline, one barrier per stage).
// Sims round-trip LDS as bf16 (XOR-16 swizzle) -> per-query scan threads.
// LDS: 2*16KB staging + 32KB sims = 64KB exactly.
// ---------------------------------------------------------------------------
__global__ __launch_bounds__(512)
void sims_topk(const float* __restrict__ weight, const u16* __restrict__ qn_bf,
               float* __restrict__ cand_val, int* __restrict__ cand_idx)
{
  __shared__ float stage[2][64*64];   // [buf][k*64+n] fp32
  __shared__ u16  simt[256*64];       // [q][n^swz] bf16
  const int tid = threadIdx.x;
  const int wave = tid >> 6, lane = tid & 63;
  const int g = lane >> 4, ln = lane & 15;

  // A fragments: qn rows for this wave, all of K=256. 64 VGPR, loaded once.
  short8 aF[2][8];
#pragma unroll
  for (int rf = 0; rf < 2; rf++)
#pragma unroll
    for (int ks = 0; ks < 8; ks++) {
      int row = wave*32 + rf*16 + ln;
      aF[rf][ks] = *(const short8*)(qn_bf + row*D_DIM + ks*32 + g*8);
    }

  float tv[8]; int ti[8];
#pragma unroll
  for (int r = 0; r < 8; r++) { tv[r] = -1e30f; ti[r] = 0; }

  const int nmine = (NCHUNKS - 1 - (int)blockIdx.x)/K2_GRID + 1;
  const int kloc = wave*4 + g;        // staging k-row within 32-row half
  const int nq   = 4*ln;              // staging col quad

  // prologue: stage chunk0 slab0 into buf0
  {
    int nn = (int)blockIdx.x*64 + nq; if (nn > N_DB-4) nn = N_DB-4;
    gload16(weight + (size_t)(kloc)*N_DB + nn,        &stage[0][wave*256]);
    gload16(weight + (size_t)(32 + kloc)*N_DB + nn,   &stage[0][2048 + wave*256]);
  }
  __syncthreads();

  f32x4 acc[2][4];
  int chunk = blockIdx.x;
  for (int m = 0; m < nmine; m++, chunk += K2_GRID) {
    const int n0 = chunk*64;
#pragma unroll
    for (int rf = 0; rf < 2; rf++)
#pragma unroll
      for (int cf = 0; cf < 4; cf++)
        acc[rf][cf] = (f32x4){0.f,0.f,0.f,0.f};

#pragma unroll
    for (int slab = 0; slab < 4; slab++) {
      // issue next stage's loads (overlaps this stage's compute)
      {
        int nchunk = (slab < 3) ? chunk : chunk + K2_GRID;
        int nslab  = (slab < 3) ? slab + 1 : 0;
        bool do_issue = (slab < 3) || (m + 1 < nmine);
        if (do_issue) {
          int nn = nchunk*64 + nq; if (nn > N_DB-4) nn = N_DB-4;
          float* lb = &stage[(slab+1)&1][0];
          gload16(weight + (size_t)(nslab*64 + kloc)*N_DB + nn,      lb + wave*256);
          gload16(weight + (size_t)(nslab*64 + 32 + kloc)*N_DB + nn, lb + 2048 + wave*256);
        }
      }
      // compute current stage
      const float* sb = &stage[slab&1][0];
#pragma unroll
      for (int ks2 = 0; ks2 < 2; ks2++) {
#pragma unroll
        for (int cf = 0; cf < 4; cf++) {
          const int nb = cf*16 + ln;
          const int kb = ks2*32 + g*8;
          float f[8];
#pragma unroll
          for (int j = 0; j < 8; j++) f[j] = sb[(kb + j)*64 + nb];
          short8 bfr;
#pragma unroll
          for (int j = 0; j < 8; j++) bfr[j] = (short)f2bf(f[j]);
          acc[0][cf] = MFMA16x16(aF[0][slab*2+ks2], bfr, acc[0][cf]);
          acc[1][cf] = MFMA16x16(aF[1][slab*2+ks2], bfr, acc[1][cf]);
        }
      }
      __syncthreads();   // drains vmcnt -> next buf ready; all done reading cur
    }

    // write sims tile (bf16, XOR-16 swizzle -> 2-way bank conflicts only)
#pragma unroll
    for (int rf = 0; rf < 2; rf++)
#pragma unroll
      for (int cf = 0; cf < 4; cf++)
#pragma unroll
        for (int r = 0; r < 4; r++) {
          int q = wave*32 + rf*16 + g*4 + r;   // D frag: row=(l>>4)*4+reg
          int n = cf*16 + ln;                   //          col=lane&15
          simt[q*64 + (n ^ ((q & 4) << 2))] = f2bf(acc[rf][cf][r]);
        }
    __syncthreads();

    // per-query scan: thread q keeps running top-8 in registers
    if (tid < 256) {
      const int q = tid;
      const int xq = (q & 4) << 2;
      for (int i = 0; i < 64; i++) {
        int j = (i + q) & 63;                  // rotation vs bank clustering
        if (n0 + j < N_DB) {
          float v = bf2f(simt[q*64 + (j ^ xq)]);
          if (v > tv[7]) {
            float cvv = v; int cn = n0 + j;
#pragma unroll
            for (int r = 0; r < 8; r++) {      // constant-index bubble insert
              if (cvv > tv[r]) {
                float tf = tv[r]; tv[r] = cvv; cvv = tf;
                int   tn = ti[r]; ti[r] = cn;  cn  = tn;
              }
            }
          }
        }
      }
    }
    // no barrier needed: next simt writes are behind 4 stage barriers
  }

  if (tid < 256) {
#pragma unroll
    for (int r = 0; r < 8; r++) {
      cand_val[((size_t)blockIdx.x*256 + tid)*8 + r] = tv[r];
      cand_idx[((size_t)blockIdx.x*256 + tid)*8 + r] = ti[r];
    }
  }
}

// ---------------------------------------------------------------------------
// K3: per-query merge of 256 blocks x 8 candidates -> approx top-8, exact
// fp32 rescore of those 8, sort (value desc, idx asc), emit top-3 +
// retrieval logits. grid=256 (q), block=256.
// ---------------------------------------------------------------------------
__global__ __launch_bounds__(256)
void merge_topk(const float* __restrict__ cand_val, const int* __restrict__ cand_idx,
                const float* __restrict__ qn, const float* __restrict__ weight,
                const int* __restrict__ label,
                float* __restrict__ scores, int* __restrict__ sidx,
                int* __restrict__ slabels, float* __restrict__ retr)
{
  __shared__ float cv[2048];
  __shared__ int   ci[2048];
  __shared__ float rv[4]; __shared__ int rp[4];
  __shared__ int   wins[8];
  __shared__ float exv[8];
  const int q = blockIdx.x, t = threadIdx.x;
#pragma unroll
  for (int r = 0; r < 8; r++) {
    cv[t*8 + r] = cand_val[((size_t)t*256 + q)*8 + r];
    ci[t*8 + r] = cand_idx[((size_t)t*256 + q)*8 + r];
  }
  __syncthreads();
  for (int round = 0; round < 8; round++) {
    float bv = -1e30f; int bp = 0;
#pragma unroll
    for (int r = 0; r < 8; r++) { float v = cv[t*8+r]; if (v > bv) { bv = v; bp = t*8+r; } }
#pragma unroll
    for (int off = 32; off; off >>= 1) {
      float ov = __shfl_xor(bv, off); int op = __shfl_xor(bp, off);
      if (ov > bv || (ov == bv && op < bp)) { bv = ov; bp = op; }
    }
    if ((t & 63) == 0) { rv[t>>6] = bv; rp[t>>6] = bp; }
    __syncthreads();
    if (t == 0) {
      float b2 = -1e30f; int p2 = 0;
#pragma unroll
      for (int w = 0; w < 4; w++)
        if (rv[w] > b2 || (rv[w] == b2 && rp[w] < p2)) { b2 = rv[w]; p2 = rp[w]; }
      wins[round] = ci[p2];
      cv[p2] = -1e30f;
    }
    __syncthreads();
  }
  // exact fp32 rescore of the 8 winners
  for (int r = 0; r < 8; r++) {
    const int col = wins[r];
    float p = qn[q*256 + t] * weight[(size_t)t*N_DB + col];
#pragma unroll
    for (int off = 32; off; off >>= 1) p += __shfl_xor(p, off);
    if ((t & 63) == 0) rv[t>>6] = p;
    __syncthreads();
    if (t == 0) exv[r] = rv[0] + rv[1] + rv[2] + rv[3];
    __syncthreads();
  }
  if (t == 0) {
    float v[8]; int ix[8];
#pragma unroll
    for (int r = 0; r < 8; r++) { v[r] = exv[r]; ix[r] = wins[r]; }
#pragma unroll
    for (int a = 0; a < 8; a++)
#pragma unroll
      for (int b = 0; b < 7; b++) {
        bool sw = (v[b] < v[b+1]) || (v[b] == v[b+1] && ix[b] > ix[b+1]);
        if (sw) {
          float tf = v[b]; v[b] = v[b+1]; v[b+1] = tf;
          int   tn = ix[b]; ix[b] = ix[b+1]; ix[b+1] = tn;
        }
      }
    int lb[3];
#pragma unroll
    for (int k = 0; k < 3; k++) {
      scores[q*3 + k] = v[k];
      sidx[q*3 + k]   = ix[k];
      lb[k] = label[ix[k]];
      slabels[q*3 + k] = lb[k];
    }
#pragma unroll
    for (int c = 0; c < NLBL; c++) {
      float cnt = (float)((lb[0]==c) + (lb[1]==c) + (lb[2]==c));
      retr[q*NLBL + c] = cnt * (1.0f/3.0f);
    }
  }
}

// ---------------------------------------------------------------------------
// K4: build H = [CLS; x; r] rows, (768 seqs)x3x256. grid=768, block=256.
// ---------------------------------------------------------------------------
__global__ __launch_bounds__(256)
void build_h(const float* __restrict__ queries, const float* __restrict__ weight,
             const float* __restrict__ scores, const int* __restrict__ sidx,
             const int* __restrict__ slabels, float* __restrict__ H)
{
  const int s = blockIdx.x, d = threadIdx.x;
  const int col = sidx[s]; const int lbl = slabels[s]; const float sc = scores[s];
  H[((size_t)s*3 + 0)*256 + d] = (d == lbl) ? sc : 0.0f;
  H[((size_t)s*3 + 1)*256 + d] = queries[(s/3)*256 + d];
  H[((size_t)s*3 + 2)*256 + d] = weight[(size_t)d*N_DB + col];
}

// ---------------------------------------------------------------------------
// GEMM (K=256 fixed): C[M][N] = A(f32,lda) @ BT(bf16 [n][k])^T + bias, bf16
// MFMA, fragments direct from global (everything L2-resident).
// grid = (M/64, N/64), block = 256 (4 waves, 2x2 of 32x32 tiles).
// ---------------------------------------------------------------------------
template<int TANH>
__global__ __launch_bounds__(256)
void gemm_k256(const float* __restrict__ A, int lda,
               const u16* __restrict__ BT, const float* __restrict__ bias,
               float* __restrict__ C, int ldc)
{
  const int tid = threadIdx.x;
  const int wave = tid >> 6, lane = tid & 63;
  const int g = lane >> 4, ln = lane & 15;
  const int wr = wave >> 1, wc = wave & 1;
  const int m0 = blockIdx.x*64 + wr*32;
  const int n0 = blockIdx.y*64 + wc*32;
  f32x4 acc[2][2];
#pragma unroll
  for (int a = 0; a < 2; a++)
#pragma unroll
    for (int b = 0; b < 2; b++) acc[a][b] = (f32x4){0.f,0.f,0.f,0.f};
  for (int k0 = 0; k0 < 256; k0 += 32) {
    short8 af[2], bf_[2];
#pragma unroll
    for (int rf = 0; rf < 2; rf++) {
      const float* ap = A + (size_t)(m0 + rf*16 + ln)*lda + k0 + g*8;
      f32x4 v0 = *(const f32x4*)ap;
      f32x4 v1 = *(const f32x4*)(ap + 4);
      short8 tt;
#pragma unroll
      for (int j = 0; j < 4; j++) { tt[j] = (short)f2bf(v0[j]); tt[4+j] = (short)f2bf(v1[j]); }
      af[rf] = tt;
    }
#pragma unroll
    for (int cf = 0; cf < 2; cf++)
      bf_[cf] = *(const short8*)(BT + (size_t)(n0 + cf*16 + ln)*256 + k0 + g*8);
#pragma unroll
    for (int rf = 0; rf < 2; rf++)
#pragma unroll
      for (int cf = 0; cf < 2; cf++)
        acc[rf][cf] = MFMA16x16(af[rf], bf_[cf], acc[rf][cf]);
  }
#pragma unroll
  for (int rf = 0; rf < 2; rf++)
#pragma unroll
    for (int cf = 0; cf < 2; cf++)
#pragma unroll
      for (int r = 0; r < 4; r++) {
        const int row = m0 + rf*16 + g*4 + r;
        const int col = n0 + cf*16 + ln;
        float v = acc[rf][cf][r] + bias[col];
        if (TANH) v = tanhf(v);
        C[(size_t)row*ldc + col] = v;
      }
}

// ---------------------------------------------------------------------------
// K6: per-sequence 3x3 attention. grid=768, block=64 (1 wave).
// ---------------------------------------------------------------------------
__global__ __launch_bounds__(64)
void attn3(const float* __restrict__ QKV, float* __restrict__ Att)
{
  const int s = blockIdx.x, l = threadIdx.x;
  const float* base = QKV + (size_t)s*3*768;
  f32x4 Q[3], Kv[3], V[3];
#pragma unroll
  for (int i = 0; i < 3; i++) {
    Q[i]  = *(const f32x4*)(base + i*768 +   0 + l*4);
    Kv[i] = *(const f32x4*)(base + i*768 + 256 + l*4);
    V[i]  = *(const f32x4*)(base + i*768 + 512 + l*4);
  }
  float S[3][3];
#pragma unroll
  for (int i = 0; i < 3; i++)
#pragma unroll
    for (int j = 0; j < 3; j++) {
      float p = Q[i][0]*Kv[j][0] + Q[i][1]*Kv[j][1] + Q[i][2]*Kv[j][2] + Q[i][3]*Kv[j][3];
#pragma unroll
      for (int off = 32; off; off >>= 1) p += __shfl_xor(p, off);
      S[i][j] = p * 0.125f;   // 1/sqrt(dk=64)
    }
#pragma unroll
  for (int i = 0; i < 3; i++) {
    float mx = fmaxf(S[i][0], fmaxf(S[i][1], S[i][2]));
    float e0 = expf(S[i][0]-mx), e1 = expf(S[i][1]-mx), e2 = expf(S[i][2]-mx);
    float inv = 1.0f / (e0 + e1 + e2);
    f32x4 o;
#pragma unroll
    for (int c = 0; c < 4; c++) o[c] = (e0*V[0][c] + e1*V[1][c] + e2*V[2][c]) * inv;
    *(f32x4*)(Att + ((size_t)s*3 + i)*256 + l*4) = o;
  }
}

// ---------------------------------------------------------------------------
// K9: logits = mean_k(x @ out_w + out_b), mix with retrieval. grid=256, blk=64.
// ---------------------------------------------------------------------------
__global__ __launch_bounds__(64)
void final_out(const float* __restrict__ x, const float* __restrict__ out_w,
               const float* __restrict__ out_b, const float* __restrict__ retr,
               float* __restrict__ out)
{
  const int q = blockIdx.x, l = threadIdx.x;
  float acc[12];
#pragma unroll
  for (int c = 0; c < 12; c++) acc[c] = 0.f;
  for (int k = 0; k < 3; k++) {
    f32x4 xv = *(const f32x4*)(x + ((size_t)q*3 + k)*256 + l*4);
#pragma unroll
    for (int c = 0; c < 12; c++) {
      acc[c] += xv[0]*out_w[(l*4+0)*12 + c] + xv[1]*out_w[(l*4+1)*12 + c]
              + xv[2]*out_w[(l*4+2)*12 + c] + xv[3]*out_w[(l*4+3)*12 + c];
    }
  }
#pragma unroll
  for (int c = 0; c < 12; c++)
#pragma unroll
    for (int off = 32; off; off >>= 1) acc[c] += __shfl_xor(acc[c], off);
  if (l == 0) {
#pragma unroll
    for (int c = 0; c < 12; c++)
      out[q*12 + c] = 0.5f*(acc[c]*(1.0f/3.0f) + out_b[c]) + 0.5f*retr[q*12 + c];
  }
}

// ---------------------------------------------------------------------------
extern "C" void kernel_launch(void* const* d_in, const int* in_sizes, int n_in,
                              void* d_out, int out_size, void* d_ws, size_t ws_size,
                              hipStream_t stream) {
  const float* queries = (const float*)d_in[0];
  const float* weight  = (const float*)d_in[1];
  const int*   label   = (const int*)  d_in[2];
  const float* Wq      = (const float*)d_in[3];
  const float* bq      = (const float*)d_in[4];
  const float* Wk      = (const float*)d_in[5];
  const float* bk      = (const float*)d_in[6];
  const float* Wv      = (const float*)d_in[7];
  const float* bv      = (const float*)d_in[8];
  const float* Wo      = (const float*)d_in[9];
  const float* bo      = (const float*)d_in[10];
  const float* dense_w = (const float*)d_in[11];
  const float* dense_b = (const float*)d_in[12];
  const float* out_w   = (const float*)d_in[13];
  const float* out_b   = (const float*)d_in[14];
  float* outp = (float*)d_out;
  char* ws = (char*)d_ws;

  // workspace layout (bytes), 256-aligned
  constexpr size_t OFF_QN     = 0;          // 256*256*4
  constexpr size_t OFF_QNBF   = 262144;     // 256*256*2
  constexpr size_t OFF_WQKVT  = 393216;     // 2*768*256*2
  constexpr size_t OFF_WOT    = 1179648;    // 2*256*256*2
  constexpr size_t OFF_DENSET = 1441792;    // 256*256*2
  constexpr size_t OFF_BQKV   = 1572864;    // 2*768*4
  constexpr size_t OFF_CVAL   = 1579008;    // 256*256*8*4
  constexpr size_t OFF_CIDX   = 3676160;    // 256*256*8*4
  constexpr size_t OFF_SCORES = 5773312;    // 256*3*4
  constexpr size_t OFF_SIDX   = 5776384;
  constexpr size_t OFF_SLAB   = 5779456;
  constexpr size_t OFF_RETR   = 5782528;    // 256*12*4
  constexpr size_t OFF_HCAT   = 5794816;    // 2304*256*4
  constexpr size_t OFF_QKV    = 8154112;    // 2304*768*4
  constexpr size_t OFF_ATT    = 15232000;   // 2304*256*4
  constexpr size_t OFF_H1     = 17591296;   // 2304*256*4
  constexpr size_t OFF_H2     = 19950592;   // 2304*256*4
  constexpr size_t OFF_X      = 22309888;   // 768*256*4  (end ~23.1MB)

  float* qn      = (float*)(ws + OFF_QN);
  u16*   qn_bf   = (u16*)  (ws + OFF_QNBF);
  u16*   WqkvT   = (u16*)  (ws + OFF_WQKVT);
  u16*   WoT     = (u16*)  (ws + OFF_WOT);
  u16*   denseT  = (u16*)  (ws + OFF_DENSET);
  float* bqkv    = (float*)(ws + OFF_BQKV);
  float* cval    = (float*)(ws + OFF_CVAL);
  int*   cidx    = (int*)  (ws + OFF_CIDX);
  float* scores  = (float*)(ws + OFF_SCORES);
  int*   sidx    = (int*)  (ws + OFF_SIDX);
  int*   slabels = (int*)  (ws + OFF_SLAB);
  float* retr    = (float*)(ws + OFF_RETR);
  float* Hcat    = (float*)(ws + OFF_HCAT);
  float* QKV     = (float*)(ws + OFF_QKV);
  float* Att     = (float*)(ws + OFF_ATT);
  float* H1      = (float*)(ws + OFF_H1);
  float* H2      = (float*)(ws + OFF_H2);
  float* Xb      = (float*)(ws + OFF_X);

  transp<<<2304, 256, 0, stream>>>(Wq, Wk, Wv, Wo, dense_w, bq, bk, bv,
                                   WqkvT, WoT, denseT, bqkv);
  prep_queries<<<256, 256, 0, stream>>>(queries, qn, qn_bf);
  sims_topk<<<K2_GRID, 512, 0, stream>>>(weight, qn_bf, cval, cidx);
  merge_topk<<<256, 256, 0, stream>>>(cval, cidx, qn, weight, label,
                                      scores, sidx, slabels, retr);
  build_h<<<768, 256, 0, stream>>>(queries, weight, scores, sidx, slabels, Hcat);
  // layer 0
  gemm_k256<0><<<dim3(36,12), 256, 0, stream>>>(Hcat, 256, WqkvT, bqkv, QKV, 768);
  attn3<<<768, 64, 0, stream>>>(QKV, Att);
  gemm_k256<0><<<dim3(36,4), 256, 0, stream>>>(Att, 256, WoT, bo, H1, 256);
  // layer 1
  gemm_k256<0><<<dim3(36,12), 256, 0, stream>>>(H1, 256, WqkvT + (size_t)768*256,
                                                bqkv + 768, QKV, 768);
  attn3<<<768, 64, 0, stream>>>(QKV, Att);
  gemm_k256<0><<<dim3(36,4), 256, 0, stream>>>(Att, 256, WoT + (size_t)256*256,
                                               bo + 256, H2, 256);
  // dense (rows = position 0 of each seq) + tanh
  gemm_k256<1><<<dim3(12,4), 256, 0, stream>>>(H2, 768, denseT, dense_b, Xb, 256);
  final_out<<<256, 64, 0, stream>>>(Xb, out_w, out_b, retr, outp);

  (void)in_sizes; (void)n_in; (void)out_size; (void)ws_size;
}